// Round 1
// baseline (463.197 us; speedup 1.0000x reference)
//
#include <hip/hip_runtime.h>

#define KH 5
#define KW 5
#define CIN 16
#define NF 32
#define H 224
#define W 224
#define HO 220
#define WO 220

// One block per (b, ho, c). Stage channel-c input rows + channel-c weights in
// LDS; 4 waves x 8 filters; lane covers 4 consecutive wo (lanes 0..54 active).
// All math exact in fp32 (inputs < 256, |k| <= 8, 25-tap sums < 2^24).
__global__ __launch_bounds__(256) void conv2d_perchan_kernel(
    const float* __restrict__ X,   // [B, H, W, CIN]
    const float* __restrict__ Kw,  // [KH, KW, CIN, NF]
    float* __restrict__ O)         // [B, HO, CIN, NF, WO]
{
    __shared__ float xs[KH * W];        // 1120 floats: rows ho..ho+4 of channel c
    __shared__ float ws[KH * KW * NF];  // 800 floats: k[i,j,c,:]

    const int c  = blockIdx.x;
    const int ho = blockIdx.y;
    const int b  = blockIdx.z;
    const int t  = threadIdx.x;

    // ---- stage input: x[b, ho+i, w, c], strided gather by CIN floats ----
    const float* xbase = X + ((size_t)(b * H + ho) * W) * CIN + c;
    for (int idx = t; idx < KH * W; idx += 256) {
        xs[idx] = xbase[(size_t)idx * CIN];   // idx = i*W + w; global row stride W*CIN matches
    }
    // ---- stage weights: k[tap, c, f], f contiguous ----
    for (int idx = t; idx < KH * KW * NF; idx += 256) {
        const int tap = idx >> 5;   // /NF
        const int f   = idx & 31;
        ws[idx] = Kw[(size_t)tap * (CIN * NF) + c * NF + f];
    }
    __syncthreads();

    const int wave = t >> 6;
    const int lane = t & 63;
    const int f0   = wave * 8;
    const int wo0  = lane * 4;
    if (lane >= 55) return;   // 55 * 4 = 220 = WO; no later barrier

    float acc[8][4];
#pragma unroll
    for (int f = 0; f < 8; ++f)
#pragma unroll
        for (int r = 0; r < 4; ++r) acc[f][r] = 0.0f;

#pragma unroll
    for (int i = 0; i < KH; ++i) {
        // 8 consecutive x values cover taps j=0..4 for wo0..wo0+3
        const float4 xa = *(const float4*)&xs[i * W + wo0];
        const float4 xb = *(const float4*)&xs[i * W + wo0 + 4];
        float xr[8] = {xa.x, xa.y, xa.z, xa.w, xb.x, xb.y, xb.z, xb.w};
#pragma unroll
        for (int j = 0; j < KW; ++j) {
            // wave-uniform address -> LDS broadcast, conflict-free
            const float4 w0 = *(const float4*)&ws[(i * KW + j) * NF + f0];
            const float4 w1 = *(const float4*)&ws[(i * KW + j) * NF + f0 + 4];
            const float wv[8] = {w0.x, w0.y, w0.z, w0.w, w1.x, w1.y, w1.z, w1.w};
#pragma unroll
            for (int f = 0; f < 8; ++f)
#pragma unroll
                for (int r = 0; r < 4; ++r)
                    acc[f][r] += xr[j + r] * wv[f];
        }
    }

    // ---- store: out[b, ho, c, f0+f, wo0..wo0+3], aligned float4 ----
    const size_t obase = (((size_t)(b * HO + ho) * CIN + c) * NF + f0) * WO + wo0;
#pragma unroll
    for (int f = 0; f < 8; ++f) {
        *(float4*)&O[obase + (size_t)f * WO] =
            make_float4(acc[f][0], acc[f][1], acc[f][2], acc[f][3]);
    }
}

extern "C" void kernel_launch(void* const* d_in, const int* in_sizes, int n_in,
                              void* d_out, int out_size, void* d_ws, size_t ws_size,
                              hipStream_t stream) {
    const float* X  = (const float*)d_in[0];
    const float* Kw = (const float*)d_in[1];
    float* O        = (float*)d_out;

    dim3 grid(CIN, HO, 4);   // (c, ho, b)
    conv2d_perchan_kernel<<<grid, 256, 0, stream>>>(X, Kw, O);
}

// Round 2
// 454.020 us; speedup vs baseline: 1.0202x; 1.0202x over previous
//
#include <hip/hip_runtime.h>

#define KH 5
#define KW 5
#define CIN 16
#define NF 32
#define H 224
#define W 224
#define HO 220
#define WO 220

// One block per (b, ho, c). Stage the 5 input rows of channel c in LDS, read
// them ONCE into registers (10 ds_read_b128/wave). Weights are wave-uniform:
// per filter, 25 scalar loads from global (readfirstlane-forced uniform
// address -> s_load, K$-cached, zero LDS traffic). 4 waves x 8 filters;
// lane covers 4 consecutive wo (lanes 0..54 active).
// Math exact in fp32 (x < 256, |k| <= 8, 25-tap sums < 2^24).
__global__ __launch_bounds__(256) void conv2d_perchan_kernel(
    const float* __restrict__ X,   // [B, H, W, CIN]
    const float* __restrict__ Kw,  // [KH, KW, CIN, NF]
    float* __restrict__ O)         // [B, HO, CIN, NF, WO]
{
    __shared__ float xs[KH * W];   // 1120 floats: rows ho..ho+4 of channel c

    const int c  = blockIdx.x;
    const int ho = blockIdx.y;
    const int b  = blockIdx.z;
    const int t  = threadIdx.x;

    // ---- stage input: x[b, ho+i, w, c], strided gather by CIN floats ----
    const float* xbase = X + ((size_t)(b * H + ho) * W) * CIN + c;
    for (int idx = t; idx < KH * W; idx += 256) {
        xs[idx] = xbase[(size_t)idx * CIN];   // idx = i*W + w
    }
    __syncthreads();

    const int wave = t >> 6;
    const int lane = t & 63;
    const int wo0  = lane * 4;
    if (lane >= 55) return;   // 55 * 4 = 220 = WO; no barrier after this

    // ---- x window into registers: 5 rows x 8 floats (covers taps j+r) ----
    float xr[KH][8];
#pragma unroll
    for (int i = 0; i < KH; ++i) {
        const float4 xa = *(const float4*)&xs[i * W + wo0];
        const float4 xb = *(const float4*)&xs[i * W + wo0 + 4];
        xr[i][0] = xa.x; xr[i][1] = xa.y; xr[i][2] = xa.z; xr[i][3] = xa.w;
        xr[i][4] = xb.x; xr[i][5] = xb.y; xr[i][6] = xb.z; xr[i][7] = xb.w;
    }

    const float* kwc = Kw + c * NF;                 // + tap*(CIN*NF) + f
    const size_t orow = (((size_t)(b * HO + ho) * CIN + c) * NF) * WO + wo0;

#pragma unroll 2
    for (int fi = 0; fi < 8; ++fi) {
        // wave-uniform filter index -> scalar loads for the 25 weights
        const int f = __builtin_amdgcn_readfirstlane(wave * 8 + fi);
        float wk[KH * KW];
#pragma unroll
        for (int tap = 0; tap < KH * KW; ++tap)
            wk[tap] = kwc[(size_t)tap * (CIN * NF) + f];

        float acc0 = 0.f, acc1 = 0.f, acc2 = 0.f, acc3 = 0.f;
#pragma unroll
        for (int i = 0; i < KH; ++i)
#pragma unroll
            for (int j = 0; j < KW; ++j) {
                const float w = wk[i * KW + j];
                acc0 += xr[i][j + 0] * w;
                acc1 += xr[i][j + 1] * w;
                acc2 += xr[i][j + 2] * w;
                acc3 += xr[i][j + 3] * w;
            }

        *(float4*)&O[orow + (size_t)f * WO] = make_float4(acc0, acc1, acc2, acc3);
    }
}

extern "C" void kernel_launch(void* const* d_in, const int* in_sizes, int n_in,
                              void* d_out, int out_size, void* d_ws, size_t ws_size,
                              hipStream_t stream) {
    const float* X  = (const float*)d_in[0];
    const float* Kw = (const float*)d_in[1];
    float* O        = (float*)d_out;

    dim3 grid(CIN, HO, 4);   // (c, ho, b)
    conv2d_perchan_kernel<<<grid, 256, 0, stream>>>(X, Kw, O);
}

// Round 3
// 444.100 us; speedup vs baseline: 1.0430x; 1.0223x over previous
//
#include <hip/hip_runtime.h>

#define KH 5
#define KW 5
#define CIN 16
#define NF 32
#define H 224
#define W 224
#define HO 220
#define WO 220
#define RPB 4              // output rows per block
#define XROWS (RPB + KH - 1)   // 8 input rows staged
#define WPAD 32            // taps padded 25 -> 32 floats (128 B) for s_load_dwordx16

// ---- pre-kernel: transpose weights [tap][c][f] -> Wt[c][f][tap(pad 32)] ----
__global__ void transpose_weights(const float* __restrict__ Kw,
                                  float* __restrict__ Wt) {
    int idx = blockIdx.x * 256 + threadIdx.x;     // over KH*KW*CIN*NF = 12800
    if (idx < KH * KW * CIN * NF) {
        const int tap = idx / (CIN * NF);
        const int rem = idx - tap * (CIN * NF);
        const int c   = rem >> 5;                 // / NF
        const int f   = rem & 31;                 // % NF
        Wt[((size_t)(c * NF) + f) * WPAD + tap] = Kw[idx];
    }
}

// ---- main kernel: one block per (c, ho-tile of 4, b) ----
// Stage 8 input rows of channel c in LDS, read ONCE into 64 regs/lane.
// Per wave: 8 filters; per filter 25 weights via 2 s_load_dwordx16 from a
// contiguous 128-B K$ line (no K$ thrash), then 400 FMAs (4 rows x 4 wo x 25).
// Math exact in fp32 (x < 256, |k| <= 8, sums < 2^24).
__global__ __launch_bounds__(256) void conv2d_main(
    const float* __restrict__ X,    // [B, H, W, CIN]
    const float* __restrict__ Wt,   // [CIN, NF, WPAD]
    float* __restrict__ O)          // [B, HO, CIN, NF, WO]
{
    __shared__ float xs[XROWS * W];   // 7168 B

    const int c   = blockIdx.x;
    const int ho0 = blockIdx.y * RPB;
    const int b   = blockIdx.z;
    const int t   = threadIdx.x;

    // stage input rows ho0..ho0+7 of channel c (strided gather by CIN floats)
    const float* xbase = X + ((size_t)(b * H + ho0) * W) * CIN + c;
    for (int idx = t; idx < XROWS * W; idx += 256)
        xs[idx] = xbase[(size_t)idx * CIN];
    __syncthreads();

    const int wave = t >> 6;
    const int lane = t & 63;
    const int wo0  = lane * 4;
    if (lane >= 55) return;          // 55*4 = 220 = WO; no barrier after this

    // x window: 8 rows x 8 floats per lane (taps j+col for 4 wo)
    float xr[XROWS][8];
#pragma unroll
    for (int r = 0; r < XROWS; ++r) {
        const float4 xa = *(const float4*)&xs[r * W + wo0];
        const float4 xb = *(const float4*)&xs[r * W + wo0 + 4];
        xr[r][0] = xa.x; xr[r][1] = xa.y; xr[r][2] = xa.z; xr[r][3] = xa.w;
        xr[r][4] = xb.x; xr[r][5] = xb.y; xr[r][6] = xb.z; xr[r][7] = xb.w;
    }

    // per-output-row store bases (row stride CIN*NF*WO floats)
    size_t obase[RPB];
#pragma unroll
    for (int r = 0; r < RPB; ++r)
        obase[r] = (((size_t)(b * HO + ho0 + r) * CIN + c) * NF) * WO + wo0;

    const float* wc = Wt + (size_t)(c * NF) * WPAD;

#pragma unroll 1
    for (int fi = 0; fi < 8; ++fi) {
        const int f = __builtin_amdgcn_readfirstlane(wave * 8 + fi);
        const float* wp = wc + (size_t)f * WPAD;   // 128-B aligned, contiguous
        float wk[KH * KW];
#pragma unroll
        for (int tap = 0; tap < KH * KW; ++tap)
            wk[tap] = wp[tap];                     // uniform -> s_load_dwordx16 x2

        float acc[RPB][4];
#pragma unroll
        for (int r = 0; r < RPB; ++r)
#pragma unroll
            for (int q = 0; q < 4; ++q) acc[r][q] = 0.0f;

#pragma unroll
        for (int i = 0; i < KH; ++i)
#pragma unroll
            for (int j = 0; j < KW; ++j) {
                const float w = wk[i * KW + j];
#pragma unroll
                for (int r = 0; r < RPB; ++r) {
                    acc[r][0] += xr[r + i][j + 0] * w;
                    acc[r][1] += xr[r + i][j + 1] * w;
                    acc[r][2] += xr[r + i][j + 2] * w;
                    acc[r][3] += xr[r + i][j + 3] * w;
                }
            }

#pragma unroll
        for (int r = 0; r < RPB; ++r)
            *(float4*)&O[obase[r] + (size_t)f * WO] =
                make_float4(acc[r][0], acc[r][1], acc[r][2], acc[r][3]);
    }
}

extern "C" void kernel_launch(void* const* d_in, const int* in_sizes, int n_in,
                              void* d_out, int out_size, void* d_ws, size_t ws_size,
                              hipStream_t stream) {
    const float* X  = (const float*)d_in[0];
    const float* Kw = (const float*)d_in[1];
    float* O        = (float*)d_out;
    float* Wt       = (float*)d_ws;   // 16*32*32*4 = 64 KB scratch

    transpose_weights<<<dim3(50), 256, 0, stream>>>(Kw, Wt);
    dim3 grid(CIN, HO / RPB, 4);      // (c, ho-tile, b) = 16 x 55 x 4
    conv2d_main<<<grid, 256, 0, stream>>>(X, Wt, O);
}